// Round 1
// baseline (494.970 us; speedup 1.0000x reference)
//
#include <hip/hip_runtime.h>
#include <math.h>

#define BB 8192
#define DIN 1024
#define DZ 256
#define DH 256
#define DT 16
#define DREC 256

// d_out layout (floats): I_hat, z, h, z_hat, spatial, temporal, energy
#define OFF_IHAT 0
#define OFF_Z    (BB * DIN)
#define OFF_H    (OFF_Z + BB * DZ)
#define OFF_ZHAT (OFF_H + BB * DH)
#define OFF_SCAL (OFF_ZHAT + BB * DZ)

// workspace layout (floats)
#define WS_SIGMA 0
#define WS_THETA (BB * DZ)
#define WS_RAW   (WS_THETA + BB * DT)
#define WS_R1    (WS_RAW + BB * DZ)

// ---------------------------------------------------------------------------
// 64x64-tile fp32 GEMM core: C[b,n] = sum_k A[b,k] * W[n,k]  (A row-major
// [M,K], W row-major [N,K] -> both K-contiguous). 256 threads, 4x4 micro-tile
// per thread, K-tile = 16, tiles stored transposed in LDS for b128 reads.
// ---------------------------------------------------------------------------
template <bool TWO>
__device__ inline void gemm_block(const float* __restrict__ A, int lda,
                                  const float* __restrict__ W0,
                                  const float* __restrict__ W1, int ldw, int K,
                                  int row0, int col0,
                                  float (&acc0)[4][4], float (&acc1)[4][4],
                                  float (*As)[68], float (*Bs0)[68],
                                  float (*Bs1)[68]) {
  const int tid = threadIdx.x;
  const int tc = tid & 15;         // col group (4 cols)
  const int tr = tid >> 4;         // row group (4 rows)
  const int lr = tid >> 2;         // loader row 0..63
  const int lk = (tid & 3) << 2;   // loader k offset 0,4,8,12

  for (int k0 = 0; k0 < K; k0 += 16) {
    __syncthreads();
    float4 a4 = *(const float4*)(A + (size_t)(row0 + lr) * lda + (k0 + lk));
    As[lk + 0][lr] = a4.x; As[lk + 1][lr] = a4.y;
    As[lk + 2][lr] = a4.z; As[lk + 3][lr] = a4.w;
    float4 b4 = *(const float4*)(W0 + (size_t)(col0 + lr) * ldw + (k0 + lk));
    Bs0[lk + 0][lr] = b4.x; Bs0[lk + 1][lr] = b4.y;
    Bs0[lk + 2][lr] = b4.z; Bs0[lk + 3][lr] = b4.w;
    if (TWO) {
      float4 c4 = *(const float4*)(W1 + (size_t)(col0 + lr) * ldw + (k0 + lk));
      Bs1[lk + 0][lr] = c4.x; Bs1[lk + 1][lr] = c4.y;
      Bs1[lk + 2][lr] = c4.z; Bs1[lk + 3][lr] = c4.w;
    }
    __syncthreads();
#pragma unroll
    for (int kk = 0; kk < 16; ++kk) {
      float4 av = *(const float4*)&As[kk][tr << 2];
      float4 bv = *(const float4*)&Bs0[kk][tc << 2];
      float a[4] = {av.x, av.y, av.z, av.w};
      float b[4] = {bv.x, bv.y, bv.z, bv.w};
#pragma unroll
      for (int i = 0; i < 4; ++i)
#pragma unroll
        for (int j = 0; j < 4; ++j)
          acc0[i][j] = fmaf(a[i], b[j], acc0[i][j]);
      if (TWO) {
        float4 cv = *(const float4*)&Bs1[kk][tc << 2];
        float c[4] = {cv.x, cv.y, cv.z, cv.w};
#pragma unroll
        for (int i = 0; i < 4; ++i)
#pragma unroll
          for (int j = 0; j < 4; ++j)
            acc1[i][j] = fmaf(a[i], c[j], acc1[i][j]);
      }
    }
  }
}

__device__ inline float block_sum256(float v, float* rbuf) {
#pragma unroll
  for (int off = 32; off > 0; off >>= 1) v += __shfl_down(v, off, 64);
  __syncthreads();  // protect rbuf against reuse
  if ((threadIdx.x & 63) == 0) rbuf[threadIdx.x >> 6] = v;
  __syncthreads();
  return rbuf[0] + rbuf[1] + rbuf[2] + rbuf[3];
}

__device__ inline float softplus_stable(float y) {  // log(1+e^y)
  return (y > 20.f) ? y : log1pf(expf(y));
}

// ---------------------------------------------------------------------------
// k_prior: mu_p=relu(h@Wpm^T), sigma_p=softplus(1.2x)/1.2,
//          z_hat = mu_p + eps_zhat*sigma_p ; sigma_p -> ws
// ---------------------------------------------------------------------------
__global__ __launch_bounds__(256) void k_prior(
    const float* __restrict__ h_m_1, const float* __restrict__ Wmu,
    const float* __restrict__ Wlv, const float* __restrict__ eps_zhat,
    float* __restrict__ zhat_out, float* __restrict__ sigma_ws) {
  __shared__ __align__(16) float As[16][68], Bs0[16][68], Bs1[16][68];
  int col0 = blockIdx.x * 64, row0 = blockIdx.y * 64;
  float acc0[4][4] = {}, acc1[4][4] = {};
  gemm_block<true>(h_m_1, DH, Wmu, Wlv, DH, DH, row0, col0, acc0, acc1, As, Bs0, Bs1);
  int tid = threadIdx.x, tc = tid & 15, tr = tid >> 4;
#pragma unroll
  for (int i = 0; i < 4; ++i) {
    int b = row0 + (tr << 2) + i;
    int n = col0 + (tc << 2);
    float4 ez = *(const float4*)(eps_zhat + (size_t)b * DZ + n);
    float e[4] = {ez.x, ez.y, ez.z, ez.w};
    float sg[4], zh[4];
#pragma unroll
    for (int j = 0; j < 4; ++j) {
      float mu = fmaxf(acc0[i][j], 0.f);
      float sig = softplus_stable(1.2f * acc1[i][j]) * (1.f / 1.2f);
      sg[j] = sig;
      zh[j] = mu + e[j] * sig;
    }
    *(float4*)(sigma_ws + (size_t)b * DZ + n) = make_float4(sg[0], sg[1], sg[2], sg[3]);
    *(float4*)(zhat_out + (size_t)b * DZ + n) = make_float4(zh[0], zh[1], zh[2], zh[3]);
  }
}

// ---------------------------------------------------------------------------
// k_h: h = relu(z_m_1@Wz2h^T + h_m_1@Wh2h^T)
// ---------------------------------------------------------------------------
__global__ __launch_bounds__(256) void k_h(
    const float* __restrict__ z_m_1, const float* __restrict__ h_m_1,
    const float* __restrict__ Wz2h, const float* __restrict__ Wh2h,
    float* __restrict__ h_out) {
  __shared__ __align__(16) float As[16][68], Bs0[16][68], Bs1[16][68];
  int col0 = blockIdx.x * 64, row0 = blockIdx.y * 64;
  float acc0[4][4] = {}, accd[4][4];
  gemm_block<false>(z_m_1, DZ, Wz2h, nullptr, DZ, DZ, row0, col0, acc0, accd, As, Bs0, Bs1);
  gemm_block<false>(h_m_1, DH, Wh2h, nullptr, DH, DH, row0, col0, acc0, accd, As, Bs0, Bs1);
  int tid = threadIdx.x, tc = tid & 15, tr = tid >> 4;
#pragma unroll
  for (int i = 0; i < 4; ++i) {
    int b = row0 + (tr << 2) + i;
    int n = col0 + (tc << 2);
    float4 o = make_float4(fmaxf(acc0[i][0], 0.f), fmaxf(acc0[i][1], 0.f),
                           fmaxf(acc0[i][2], 0.f), fmaxf(acc0[i][3], 0.f));
    *(float4*)(h_out + (size_t)b * DH + n) = o;
  }
}

// ---------------------------------------------------------------------------
// k_post: raw_z = clip(relu(I@Wpm^T) + eps_z*relu(I@Wpl^T), 0, 1) -> ws
// ---------------------------------------------------------------------------
__global__ __launch_bounds__(256) void k_post(
    const float* __restrict__ I_t, const float* __restrict__ Wmu,
    const float* __restrict__ Wlv, const float* __restrict__ eps_z,
    float* __restrict__ raw_ws) {
  __shared__ __align__(16) float As[16][68], Bs0[16][68], Bs1[16][68];
  int col0 = blockIdx.x * 64, row0 = blockIdx.y * 64;
  float acc0[4][4] = {}, acc1[4][4] = {};
  gemm_block<true>(I_t, DIN, Wmu, Wlv, DIN, DIN, row0, col0, acc0, acc1, As, Bs0, Bs1);
  int tid = threadIdx.x, tc = tid & 15, tr = tid >> 4;
#pragma unroll
  for (int i = 0; i < 4; ++i) {
    int b = row0 + (tr << 2) + i;
    int n = col0 + (tc << 2);
    float4 ez = *(const float4*)(eps_z + (size_t)b * DZ + n);
    float e[4] = {ez.x, ez.y, ez.z, ez.w};
    float r[4];
#pragma unroll
    for (int j = 0; j < 4; ++j) {
      float mu = fmaxf(acc0[i][j], 0.f);
      float sq = fmaxf(acc1[i][j], 0.f);
      float raw = mu + e[j] * sq;
      r[j] = fminf(fmaxf(raw, 0.f), 1.f);
    }
    *(float4*)(raw_ws + (size_t)b * DZ + n) = make_float4(r[0], r[1], r[2], r[3]);
  }
}

// ---------------------------------------------------------------------------
// k_theta: theta = 0.001*softplus_beta(0.5*theta_m_1 + 0.1*I@Wi2t^T
//                                       - sigma_p@relu(Wvip2t)^T, 0.5)
// ---------------------------------------------------------------------------
__global__ __launch_bounds__(256) void k_theta(
    const float* __restrict__ I_t, const float* __restrict__ W_i2t,
    const float* __restrict__ sigma_ws, const float* __restrict__ W_vip2t,
    const float* __restrict__ theta_m_1, float* __restrict__ theta_ws) {
  __shared__ __align__(16) float As[16][68];
  __shared__ float Ws[16 * 17];
  int row0 = blockIdx.x * 64;
  int tid = threadIdx.x;
  int c = tid & 15, rg = tid >> 4;
  int lr = tid >> 2, lk = (tid & 3) << 2;
  float acc_i[4] = {0, 0, 0, 0}, acc_v[4] = {0, 0, 0, 0};

  // pass 1: I_t @ W_i2t^T  (K = 1024)
  for (int k0 = 0; k0 < DIN; k0 += 16) {
    __syncthreads();
    float4 a4 = *(const float4*)(I_t + (size_t)(row0 + lr) * DIN + k0 + lk);
    As[lk + 0][lr] = a4.x; As[lk + 1][lr] = a4.y;
    As[lk + 2][lr] = a4.z; As[lk + 3][lr] = a4.w;
    if (tid < 64) {
      int wc = tid >> 2, wk = (tid & 3) << 2;
      float4 w4 = *(const float4*)(W_i2t + (size_t)wc * DIN + k0 + wk);
      Ws[wc * 17 + wk + 0] = w4.x; Ws[wc * 17 + wk + 1] = w4.y;
      Ws[wc * 17 + wk + 2] = w4.z; Ws[wc * 17 + wk + 3] = w4.w;
    }
    __syncthreads();
#pragma unroll
    for (int kk = 0; kk < 16; ++kk) {
      float w = Ws[c * 17 + kk];
#pragma unroll
      for (int i = 0; i < 4; ++i)
        acc_i[i] = fmaf(As[kk][rg + 16 * i], w, acc_i[i]);
    }
  }
  // pass 2: sigma_p @ relu(W_vip2t)^T  (K = 256)
  for (int k0 = 0; k0 < DZ; k0 += 16) {
    __syncthreads();
    float4 a4 = *(const float4*)(sigma_ws + (size_t)(row0 + lr) * DZ + k0 + lk);
    As[lk + 0][lr] = a4.x; As[lk + 1][lr] = a4.y;
    As[lk + 2][lr] = a4.z; As[lk + 3][lr] = a4.w;
    if (tid < 64) {
      int wc = tid >> 2, wk = (tid & 3) << 2;
      float4 w4 = *(const float4*)(W_vip2t + (size_t)wc * DZ + k0 + wk);
      Ws[wc * 17 + wk + 0] = fmaxf(w4.x, 0.f); Ws[wc * 17 + wk + 1] = fmaxf(w4.y, 0.f);
      Ws[wc * 17 + wk + 2] = fmaxf(w4.z, 0.f); Ws[wc * 17 + wk + 3] = fmaxf(w4.w, 0.f);
    }
    __syncthreads();
#pragma unroll
    for (int kk = 0; kk < 16; ++kk) {
      float w = Ws[c * 17 + kk];
#pragma unroll
      for (int i = 0; i < 4; ++i)
        acc_v[i] = fmaf(As[kk][rg + 16 * i], w, acc_v[i]);
    }
  }
#pragma unroll
  for (int i = 0; i < 4; ++i) {
    int b = row0 + rg + 16 * i;
    float th = 0.5f * theta_m_1[(size_t)b * DT + c] + 0.1f * acc_i[i] - acc_v[i];
    // 0.001 * softplus_beta(th, 0.5) = 0.002 * log1p(exp(0.5*th))
    theta_ws[(size_t)b * DT + c] = 0.002f * softplus_stable(0.5f * th);
  }
}

// ---------------------------------------------------------------------------
// k_z: z = relu(raw_z - 10*theta@relu(W_t2z)^T); fused temporal & energy
// ---------------------------------------------------------------------------
__global__ __launch_bounds__(256) void k_z(
    const float* __restrict__ raw_ws, const float* __restrict__ theta_ws,
    const float* __restrict__ W_t2z, const float* __restrict__ zhat_out,
    float* __restrict__ z_out, float* __restrict__ scal) {
  __shared__ float wt[DZ * 17];
  __shared__ float th_s[32 * 16];
  __shared__ float rbuf[4];
  int tid = threadIdx.x;
  int row0 = blockIdx.x * 32;
  for (int idx = tid; idx < DZ * DT; idx += 256) {
    int n = idx >> 4, j = idx & 15;
    wt[n * 17 + j] = fmaxf(W_t2z[idx], 0.f);
  }
  th_s[tid] = theta_ws[(size_t)row0 * DT + tid];
  th_s[tid + 256] = theta_ws[(size_t)row0 * DT + tid + 256];
  __syncthreads();
  float tsum = 0.f, esum = 0.f;
  for (int r = 0; r < 32; ++r) {
    int b = row0 + r;
    float d = 0.f;
#pragma unroll
    for (int j = 0; j < 16; ++j) d = fmaf(th_s[r * 16 + j], wt[tid * 17 + j], d);
    float raw = raw_ws[(size_t)b * DZ + tid];
    float zz = fmaxf(raw - 10.f * d, 0.f);
    z_out[(size_t)b * DZ + tid] = zz;
    float dd = zz - zhat_out[(size_t)b * DZ + tid];
    tsum += dd * dd;
    esum += zz;  // z >= 0 so |z| == z
  }
  float t = block_sum256(tsum, rbuf);
  if (tid == 0) atomicAdd(scal + 1, t * (1.f / ((float)BB * DZ)));
  float e = block_sum256(esum, rbuf);
  if (tid == 0) atomicAdd(scal + 2, e * (1.f / ((float)BB * DZ)));
}

// ---------------------------------------------------------------------------
// k_rec1: r1 = z @ W_rec1^T (identity epilogue) -> ws
// ---------------------------------------------------------------------------
__global__ __launch_bounds__(256) void k_rec1(
    const float* __restrict__ z, const float* __restrict__ W_rec1,
    float* __restrict__ r1_ws) {
  __shared__ __align__(16) float As[16][68], Bs0[16][68], Bs1[16][68];
  int col0 = blockIdx.x * 64, row0 = blockIdx.y * 64;
  float acc0[4][4] = {}, accd[4][4];
  gemm_block<false>(z, DZ, W_rec1, nullptr, DZ, DZ, row0, col0, acc0, accd, As, Bs0, Bs1);
  int tid = threadIdx.x, tc = tid & 15, tr = tid >> 4;
#pragma unroll
  for (int i = 0; i < 4; ++i) {
    int b = row0 + (tr << 2) + i;
    int n = col0 + (tc << 2);
    *(float4*)(r1_ws + (size_t)b * DREC + n) =
        make_float4(acc0[i][0], acc0[i][1], acc0[i][2], acc0[i][3]);
  }
}

// ---------------------------------------------------------------------------
// k_rec2: I_hat = sigmoid(r1 @ W_rec2^T); fused spatial loss
// ---------------------------------------------------------------------------
__global__ __launch_bounds__(256) void k_rec2(
    const float* __restrict__ r1_ws, const float* __restrict__ W_rec2,
    const float* __restrict__ I_t, float* __restrict__ ihat_out,
    float* __restrict__ scal) {
  __shared__ __align__(16) float As[16][68], Bs0[16][68], Bs1[16][68];
  __shared__ float rbuf[4];
  int col0 = blockIdx.x * 64, row0 = blockIdx.y * 64;
  float acc0[4][4] = {}, accd[4][4];
  gemm_block<false>(r1_ws, DREC, W_rec2, nullptr, DREC, DREC, row0, col0, acc0, accd, As, Bs0, Bs1);
  int tid = threadIdx.x, tc = tid & 15, tr = tid >> 4;
  float lsum = 0.f;
#pragma unroll
  for (int i = 0; i < 4; ++i) {
    int b = row0 + (tr << 2) + i;
    int n = col0 + (tc << 2);
    float4 it = *(const float4*)(I_t + (size_t)b * DIN + n);
    float iv[4] = {it.x, it.y, it.z, it.w};
    float o[4];
#pragma unroll
    for (int j = 0; j < 4; ++j) {
      float ih = 1.f / (1.f + expf(-acc0[i][j]));
      o[j] = ih;
      float d = iv[j] - ih;
      lsum += d * d;
    }
    *(float4*)(ihat_out + (size_t)b * DIN + n) = make_float4(o[0], o[1], o[2], o[3]);
  }
  float s = block_sum256(lsum, rbuf);
  if (tid == 0) atomicAdd(scal + 0, s * (1.f / ((float)BB * DIN)));
}

// ---------------------------------------------------------------------------
extern "C" void kernel_launch(void* const* d_in, const int* in_sizes, int n_in,
                              void* d_out, int out_size, void* d_ws,
                              size_t ws_size, hipStream_t stream) {
  const float* I_t       = (const float*)d_in[0];
  const float* h_m_1     = (const float*)d_in[1];
  const float* z_m_1     = (const float*)d_in[2];
  const float* theta_m_1 = (const float*)d_in[3];
  const float* eps_z     = (const float*)d_in[4];
  const float* eps_zhat  = (const float*)d_in[5];
  const float* W_post_mu = (const float*)d_in[6];
  const float* W_post_lv = (const float*)d_in[7];
  const float* W_z2h     = (const float*)d_in[8];
  const float* W_h2h     = (const float*)d_in[9];
  const float* W_prior_mu= (const float*)d_in[10];
  const float* W_prior_lv= (const float*)d_in[11];
  const float* W_i2t     = (const float*)d_in[12];
  const float* W_vip2t   = (const float*)d_in[13];
  const float* W_t2z     = (const float*)d_in[14];
  const float* W_rec1    = (const float*)d_in[15];
  const float* W_rec2    = (const float*)d_in[16];

  float* out = (float*)d_out;
  float* ws = (float*)d_ws;
  float* ihat = out + OFF_IHAT;
  float* zout = out + OFF_Z;
  float* hout = out + OFF_H;
  float* zhat = out + OFF_ZHAT;
  float* scal = out + OFF_SCAL;
  float* sigma_ws = ws + WS_SIGMA;
  float* theta_ws = ws + WS_THETA;
  float* raw_ws = ws + WS_RAW;
  float* r1_ws = ws + WS_R1;

  hipMemsetAsync(scal, 0, 3 * sizeof(float), stream);

  dim3 g256(DZ / 64, BB / 64);     // 4 x 128
  dim3 g1024(DIN / 64, BB / 64);   // 16 x 128

  k_prior<<<g256, 256, 0, stream>>>(h_m_1, W_prior_mu, W_prior_lv, eps_zhat, zhat, sigma_ws);
  k_h<<<g256, 256, 0, stream>>>(z_m_1, h_m_1, W_z2h, W_h2h, hout);
  k_post<<<g256, 256, 0, stream>>>(I_t, W_post_mu, W_post_lv, eps_z, raw_ws);
  k_theta<<<BB / 64, 256, 0, stream>>>(I_t, W_i2t, sigma_ws, W_vip2t, theta_m_1, theta_ws);
  k_z<<<BB / 32, 256, 0, stream>>>(raw_ws, theta_ws, W_t2z, zhat, zout, scal);
  k_rec1<<<g256, 256, 0, stream>>>(zout, W_rec1, r1_ws);
  k_rec2<<<g1024, 256, 0, stream>>>(r1_ws, W_rec2, I_t, ihat, scal);
}

// Round 2
// 285.139 us; speedup vs baseline: 1.7359x; 1.7359x over previous
//
#include <hip/hip_runtime.h>
#include <math.h>

#define BB 8192
#define DIN 1024
#define DZ 256
#define DH 256
#define DT 16
#define DREC 256

// d_out layout (floats): I_hat, z, h, z_hat, spatial, temporal, energy
#define OFF_IHAT 0
#define OFF_Z    (BB * DIN)
#define OFF_H    (OFF_Z + BB * DZ)
#define OFF_ZHAT (OFF_H + BB * DH)
#define OFF_SCAL (OFF_ZHAT + BB * DZ)

typedef unsigned short u16;
typedef __attribute__((ext_vector_type(8))) unsigned short u16x8;
typedef __attribute__((ext_vector_type(8))) __bf16 bf16x8;
typedef __attribute__((ext_vector_type(4))) float f32x4;

// ---- workspace layout (u16 indices) --------------------------------------
// I_bf lives in d_out's I_hat region (16.8MB, overwritten only by k_rec2).
#define WS_HBF   0                     // h_m_1 bf16 [BB*DH]; reused as z_bf
#define WS_ZM1BF 2097152               // z_m_1 bf16; reused as sigma_bf, r1_bf
#define WS_W     4194304               // weights, packed in cvt order
#define W_PM  (WS_W + 0)
#define W_PL  (W_PM + 262144)
#define W_Z2H (W_PL + 262144)
#define W_H2H (W_Z2H + 65536)
#define W_PRM (W_H2H + 65536)
#define W_PRL (W_PRM + 65536)
#define W_I2T (W_PRL + 65536)          // stored pre-scaled by 0.1
#define W_VIP (W_I2T + 16384)          // stored as -relu(W)
#define W_R1  (W_VIP + 4096)
#define W_R2  (W_R1 + 65536)
#define WS_THETA_BYTES 10657792        // fp32 theta [BB*DT] after weights

#define LDA 72                          // padded LDS row stride (u16)

__device__ inline u16 f2bf(float f) {
  unsigned u = __builtin_bit_cast(unsigned, f);
  u += 0x7fff + ((u >> 16) & 1);
  return (u16)(u >> 16);
}

__device__ inline float softplus_stable(float y) {  // log(1+e^y)
  return (y > 20.f) ? y : log1pf(expf(y));
}

__device__ inline float block_sum256(float v, float* rbuf) {
#pragma unroll
  for (int off = 32; off > 0; off >>= 1) v += __shfl_down(v, off, 64);
  __syncthreads();
  if ((threadIdx.x & 63) == 0) rbuf[threadIdx.x >> 6] = v;
  __syncthreads();
  return rbuf[0] + rbuf[1] + rbuf[2] + rbuf[3];
}

// ---------------------------------------------------------------------------
// k_cvt: fp32 -> bf16 for all GEMM operands, with folded scalings.
// Segments are packed so dst index == flat index (seg0 goes to d_out region).
// ---------------------------------------------------------------------------
__global__ __launch_bounds__(256) void k_cvt(
    const float* __restrict__ I_t, const float* __restrict__ h_m_1,
    const float* __restrict__ z_m_1, const float* __restrict__ Wpm,
    const float* __restrict__ Wpl, const float* __restrict__ Wz2h,
    const float* __restrict__ Wh2h, const float* __restrict__ Wprm,
    const float* __restrict__ Wprl, const float* __restrict__ Wi2t,
    const float* __restrict__ Wv, const float* __restrict__ Wr1,
    const float* __restrict__ Wr2, u16* __restrict__ dstI,
    u16* __restrict__ dstW) {
  const int S1 = 8388608, S2 = 10485760, S3 = 12582912, S4 = 12845056,
            S5 = 13107200, S6 = 13172736, S7 = 13238272, S8 = 13303808,
            S9 = 13369344, S10 = 13385728, S11 = 13389824, S12 = 13455360,
            S13 = 13717504;
  int nchunk = S13 / 8;
  for (int c = blockIdx.x * 256 + threadIdx.x; c < nchunk;
       c += gridDim.x * 256) {
    int f = c * 8;
    const float* src;
    float scale = 1.f;
    bool nrelu = false;
    u16* dst;
    if (f < S1)       { src = I_t  + f;        dst = dstI + f; }
    else {
      dst = dstW + (f - S1);
      if (f < S2)       src = h_m_1 + (f - S1);
      else if (f < S3)  src = z_m_1 + (f - S2);
      else if (f < S4)  src = Wpm  + (f - S3);
      else if (f < S5)  src = Wpl  + (f - S4);
      else if (f < S6)  src = Wz2h + (f - S5);
      else if (f < S7)  src = Wh2h + (f - S6);
      else if (f < S8)  src = Wprm + (f - S7);
      else if (f < S9)  src = Wprl + (f - S8);
      else if (f < S10) { src = Wi2t + (f - S9);  scale = 0.1f; }
      else if (f < S11) { src = Wv   + (f - S10); nrelu = true; }
      else if (f < S12) src = Wr1  + (f - S11);
      else              src = Wr2  + (f - S12);
    }
    float4 v0 = *(const float4*)(src);
    float4 v1 = *(const float4*)(src + 4);
    float vals[8] = {v0.x, v0.y, v0.z, v0.w, v1.x, v1.y, v1.z, v1.w};
    u16x8 o;
#pragma unroll
    for (int j = 0; j < 8; ++j) {
      float x = vals[j];
      x = nrelu ? -fmaxf(x, 0.f) : x * scale;
      o[j] = f2bf(x);
    }
    *(u16x8*)(dst) = o;
  }
}

// ---------------------------------------------------------------------------
// Shared MFMA GEMM core: C[128x64] tile, BK=64, 256 threads (4 waves),
// wave w covers rows [w*32, w*32+32) as 2 m-tiles x 4 n-tiles of 16x16x32.
// A [M,K], B [N,K] both K-contiguous bf16. Accumulates into acc (and acc2
// against B1 when TWO).
// ---------------------------------------------------------------------------
template <int K, bool TWO>
__device__ inline void mfma_gemm(const u16* __restrict__ A,
                                 const u16* __restrict__ B0,
                                 const u16* __restrict__ B1, int row0,
                                 int col0, f32x4 (&acc)[2][4],
                                 f32x4 (&acc2)[2][4], u16* As, u16* Bs0,
                                 u16* Bs1) {
  const int tid = threadIdx.x;
  const int lane = tid & 63;
  const int w = tid >> 6;
  const int frow = lane & 15;
  const int fq = lane >> 4;

  for (int k0 = 0; k0 < K; k0 += 64) {
    __syncthreads();
#pragma unroll
    for (int i = 0; i < 4; ++i) {
      int c = tid + 256 * i;
      int r = c >> 3, kc = c & 7;
      u16x8 v = *(const u16x8*)(A + (size_t)(row0 + r) * K + k0 + kc * 8);
      *(u16x8*)(As + r * LDA + kc * 8) = v;
    }
#pragma unroll
    for (int i = 0; i < 2; ++i) {
      int c = tid + 256 * i;
      int r = c >> 3, kc = c & 7;
      *(u16x8*)(Bs0 + r * LDA + kc * 8) =
          *(const u16x8*)(B0 + (size_t)(col0 + r) * K + k0 + kc * 8);
      if (TWO)
        *(u16x8*)(Bs1 + r * LDA + kc * 8) =
            *(const u16x8*)(B1 + (size_t)(col0 + r) * K + k0 + kc * 8);
    }
    __syncthreads();
#pragma unroll
    for (int ks = 0; ks < 2; ++ks) {
      bf16x8 af[2], bf[4], bf2[4];
#pragma unroll
      for (int mi = 0; mi < 2; ++mi)
        af[mi] = __builtin_bit_cast(
            bf16x8, *(const u16x8*)(As + (w * 32 + mi * 16 + frow) * LDA +
                                    fq * 8 + ks * 32));
#pragma unroll
      for (int ni = 0; ni < 4; ++ni) {
        bf[ni] = __builtin_bit_cast(
            bf16x8,
            *(const u16x8*)(Bs0 + (ni * 16 + frow) * LDA + fq * 8 + ks * 32));
        if (TWO)
          bf2[ni] = __builtin_bit_cast(
              bf16x8, *(const u16x8*)(Bs1 + (ni * 16 + frow) * LDA + fq * 8 +
                                      ks * 32));
      }
#pragma unroll
      for (int mi = 0; mi < 2; ++mi)
#pragma unroll
        for (int ni = 0; ni < 4; ++ni) {
          acc[mi][ni] = __builtin_amdgcn_mfma_f32_16x16x32_bf16(
              af[mi], bf[ni], acc[mi][ni], 0, 0, 0);
          if (TWO)
            acc2[mi][ni] = __builtin_amdgcn_mfma_f32_16x16x32_bf16(
                af[mi], bf2[ni], acc2[mi][ni], 0, 0, 0);
        }
    }
  }
}

#define EPILOGUE_IDX()                          \
  const int tid = threadIdx.x;                  \
  const int lane = tid & 63;                    \
  const int w = tid >> 6;                       \
  const int frow = lane & 15;                   \
  const int fq = lane >> 4;                     \
  (void)tid

// ---------------------------------------------------------------------------
// k_h: h = relu(z_m_1@Wz2h^T + h_m_1@Wh2h^T)
// ---------------------------------------------------------------------------
__global__ __launch_bounds__(256) void k_h(const u16* __restrict__ zm1_bf,
                                           const u16* __restrict__ h_bf,
                                           const u16* __restrict__ Wz2h,
                                           const u16* __restrict__ Wh2h,
                                           float* __restrict__ h_out) {
  __shared__ __align__(16) u16 As[128 * LDA];
  __shared__ __align__(16) u16 Bs0[64 * LDA];
  int col0 = blockIdx.x * 64, row0 = blockIdx.y * 128;
  f32x4 acc[2][4];
#pragma unroll
  for (int mi = 0; mi < 2; ++mi)
#pragma unroll
    for (int ni = 0; ni < 4; ++ni) acc[mi][ni] = (f32x4){0.f, 0.f, 0.f, 0.f};
  mfma_gemm<DZ, false>(zm1_bf, Wz2h, nullptr, row0, col0, acc, acc, As, Bs0, Bs0);
  mfma_gemm<DH, false>(h_bf, Wh2h, nullptr, row0, col0, acc, acc, As, Bs0, Bs0);
  EPILOGUE_IDX();
#pragma unroll
  for (int mi = 0; mi < 2; ++mi)
#pragma unroll
    for (int ni = 0; ni < 4; ++ni)
#pragma unroll
      for (int r = 0; r < 4; ++r) {
        int m = row0 + w * 32 + mi * 16 + fq * 4 + r;
        int n = col0 + ni * 16 + frow;
        h_out[(size_t)m * DH + n] = fmaxf(acc[mi][ni][r], 0.f);
      }
}

// ---------------------------------------------------------------------------
// k_prior: z_hat = relu(h@Wpm^T) + eps*softplus_b(h@Wpl^T); sigma -> bf16 ws
// ---------------------------------------------------------------------------
__global__ __launch_bounds__(256) void k_prior(
    const u16* __restrict__ h_bf, const u16* __restrict__ Wpm,
    const u16* __restrict__ Wpl, const float* __restrict__ eps_zhat,
    float* __restrict__ zhat_out, u16* __restrict__ sigma_bf) {
  __shared__ __align__(16) u16 As[128 * LDA];
  __shared__ __align__(16) u16 Bs0[64 * LDA];
  __shared__ __align__(16) u16 Bs1[64 * LDA];
  int col0 = blockIdx.x * 64, row0 = blockIdx.y * 128;
  f32x4 acc[2][4], acc2[2][4];
#pragma unroll
  for (int mi = 0; mi < 2; ++mi)
#pragma unroll
    for (int ni = 0; ni < 4; ++ni) {
      acc[mi][ni] = (f32x4){0.f, 0.f, 0.f, 0.f};
      acc2[mi][ni] = (f32x4){0.f, 0.f, 0.f, 0.f};
    }
  mfma_gemm<DH, true>(h_bf, Wpm, Wpl, row0, col0, acc, acc2, As, Bs0, Bs1);
  EPILOGUE_IDX();
#pragma unroll
  for (int mi = 0; mi < 2; ++mi)
#pragma unroll
    for (int ni = 0; ni < 4; ++ni)
#pragma unroll
      for (int r = 0; r < 4; ++r) {
        int m = row0 + w * 32 + mi * 16 + fq * 4 + r;
        int n = col0 + ni * 16 + frow;
        float mu = fmaxf(acc[mi][ni][r], 0.f);
        float sig = softplus_stable(1.2f * acc2[mi][ni][r]) * (1.f / 1.2f);
        zhat_out[(size_t)m * DZ + n] =
            mu + eps_zhat[(size_t)m * DZ + n] * sig;
        sigma_bf[(size_t)m * DZ + n] = f2bf(sig);
      }
}

// ---------------------------------------------------------------------------
// k_theta: theta = 0.002*log1p(exp(0.5*(0.5*th_m1 + 0.1*I@Wi2t^T
//                   - sigma@relu(Wv)^T)))   [scalings pre-folded into weights]
// One 16-row m-tile per wave; single accumulator over both K segments.
// ---------------------------------------------------------------------------
__global__ __launch_bounds__(256) void k_theta(
    const u16* __restrict__ I_bf, const u16* __restrict__ Wi2t,
    const u16* __restrict__ sigma_bf, const u16* __restrict__ Wv,
    const float* __restrict__ theta_m_1, float* __restrict__ theta_ws) {
  const int tid = threadIdx.x;
  const int lane = tid & 63;
  const int w = tid >> 6;
  const int frow = lane & 15;
  const int fq = lane >> 4;
  const int m0 = blockIdx.x * 64 + w * 16;
  f32x4 acc = (f32x4){0.f, 0.f, 0.f, 0.f};
  const u16* arow = I_bf + (size_t)(m0 + frow) * DIN + fq * 8;
  const u16* brow = Wi2t + (size_t)frow * DIN + fq * 8;
#pragma unroll
  for (int ks = 0; ks < DIN / 32; ++ks) {
    bf16x8 a = __builtin_bit_cast(bf16x8, *(const u16x8*)(arow + ks * 32));
    bf16x8 b = __builtin_bit_cast(bf16x8, *(const u16x8*)(brow + ks * 32));
    acc = __builtin_amdgcn_mfma_f32_16x16x32_bf16(a, b, acc, 0, 0, 0);
  }
  const u16* arow2 = sigma_bf + (size_t)(m0 + frow) * DZ + fq * 8;
  const u16* brow2 = Wv + (size_t)frow * DZ + fq * 8;
#pragma unroll
  for (int ks = 0; ks < DZ / 32; ++ks) {
    bf16x8 a = __builtin_bit_cast(bf16x8, *(const u16x8*)(arow2 + ks * 32));
    bf16x8 b = __builtin_bit_cast(bf16x8, *(const u16x8*)(brow2 + ks * 32));
    acc = __builtin_amdgcn_mfma_f32_16x16x32_bf16(a, b, acc, 0, 0, 0);
  }
#pragma unroll
  for (int r = 0; r < 4; ++r) {
    int m = m0 + fq * 4 + r;
    float th = 0.5f * theta_m_1[(size_t)m * DT + frow] + acc[r];
    theta_ws[(size_t)m * DT + frow] = 0.002f * softplus_stable(0.5f * th);
  }
}

// ---------------------------------------------------------------------------
// k_post: dual GEMM (mu_q, sigma_q) K=1024 + fused z epilogue:
//   z = relu(clip(relu(mu)+eps*relu(sig),0,1) - 10*theta@relu(Wt2z)^T)
// plus temporal & energy reductions.
// ---------------------------------------------------------------------------
__global__ __launch_bounds__(256) void k_post(
    const u16* __restrict__ I_bf, const u16* __restrict__ Wpm,
    const u16* __restrict__ Wpl, const float* __restrict__ eps_z,
    const float* __restrict__ theta_ws, const float* __restrict__ W_t2z,
    const float* __restrict__ zhat, float* __restrict__ z_out,
    u16* __restrict__ z_bf, float* __restrict__ scal) {
  __shared__ __align__(16) u16 As[128 * LDA];
  __shared__ __align__(16) u16 Bs0[64 * LDA];
  __shared__ __align__(16) u16 Bs1[64 * LDA];
  __shared__ float rbuf[4];
  int col0 = blockIdx.x * 64, row0 = blockIdx.y * 128;
  f32x4 acc[2][4], acc2[2][4];
#pragma unroll
  for (int mi = 0; mi < 2; ++mi)
#pragma unroll
    for (int ni = 0; ni < 4; ++ni) {
      acc[mi][ni] = (f32x4){0.f, 0.f, 0.f, 0.f};
      acc2[mi][ni] = (f32x4){0.f, 0.f, 0.f, 0.f};
    }
  mfma_gemm<DIN, true>(I_bf, Wpm, Wpl, row0, col0, acc, acc2, As, Bs0, Bs1);
  EPILOGUE_IDX();
  // stage theta tile (128x16) and 10*relu(W_t2z) tile (64x16) in LDS
  __syncthreads();
  float* th_s = (float*)As;   // 128*17 floats
  float* wt_s = (float*)Bs0;  // 64*17 floats
  for (int idx = tid; idx < 128 * 16; idx += 256) {
    int r = idx >> 4, j = idx & 15;
    th_s[r * 17 + j] = theta_ws[(size_t)(row0 + r) * DT + j];
  }
  for (int idx = tid; idx < 64 * 16; idx += 256) {
    int n = idx >> 4, j = idx & 15;
    wt_s[n * 17 + j] = 10.f * fmaxf(W_t2z[(col0 + n) * DT + j], 0.f);
  }
  __syncthreads();
  float tsum = 0.f, esum = 0.f;
#pragma unroll
  for (int mi = 0; mi < 2; ++mi)
#pragma unroll
    for (int ni = 0; ni < 4; ++ni)
#pragma unroll
      for (int r = 0; r < 4; ++r) {
        int lr = w * 32 + mi * 16 + fq * 4 + r;
        int ln = ni * 16 + frow;
        int m = row0 + lr;
        int n = col0 + ln;
        float mu = fmaxf(acc[mi][ni][r], 0.f);
        float sq = fmaxf(acc2[mi][ni][r], 0.f);
        float raw = mu + eps_z[(size_t)m * DZ + n] * sq;
        raw = fminf(fmaxf(raw, 0.f), 1.f);
        float thr = 0.f;
#pragma unroll
        for (int j = 0; j < 16; ++j)
          thr = fmaf(th_s[lr * 17 + j], wt_s[ln * 17 + j], thr);
        float zz = fmaxf(raw - thr, 0.f);
        z_out[(size_t)m * DZ + n] = zz;
        z_bf[(size_t)m * DZ + n] = f2bf(zz);
        float d = zz - zhat[(size_t)m * DZ + n];
        tsum += d * d;
        esum += zz;
      }
  float t = block_sum256(tsum, rbuf);
  if (tid == 0) atomicAdd(scal + 1, t * (1.f / ((float)BB * DZ)));
  float e = block_sum256(esum, rbuf);
  if (tid == 0) atomicAdd(scal + 2, e * (1.f / ((float)BB * DZ)));
}

// ---------------------------------------------------------------------------
// k_rec1: r1 = z @ W_rec1^T -> bf16 ws
// ---------------------------------------------------------------------------
__global__ __launch_bounds__(256) void k_rec1(const u16* __restrict__ z_bf,
                                              const u16* __restrict__ Wr1,
                                              u16* __restrict__ r1_bf) {
  __shared__ __align__(16) u16 As[128 * LDA];
  __shared__ __align__(16) u16 Bs0[64 * LDA];
  int col0 = blockIdx.x * 64, row0 = blockIdx.y * 128;
  f32x4 acc[2][4];
#pragma unroll
  for (int mi = 0; mi < 2; ++mi)
#pragma unroll
    for (int ni = 0; ni < 4; ++ni) acc[mi][ni] = (f32x4){0.f, 0.f, 0.f, 0.f};
  mfma_gemm<DZ, false>(z_bf, Wr1, nullptr, row0, col0, acc, acc, As, Bs0, Bs0);
  EPILOGUE_IDX();
#pragma unroll
  for (int mi = 0; mi < 2; ++mi)
#pragma unroll
    for (int ni = 0; ni < 4; ++ni)
#pragma unroll
      for (int r = 0; r < 4; ++r) {
        int m = row0 + w * 32 + mi * 16 + fq * 4 + r;
        int n = col0 + ni * 16 + frow;
        r1_bf[(size_t)m * DREC + n] = f2bf(acc[mi][ni][r]);
      }
}

// ---------------------------------------------------------------------------
// k_rec2: I_hat = sigmoid(r1 @ W_rec2^T); fused spatial loss
// ---------------------------------------------------------------------------
__global__ __launch_bounds__(256) void k_rec2(const u16* __restrict__ r1_bf,
                                              const u16* __restrict__ Wr2,
                                              const float* __restrict__ I_t,
                                              float* __restrict__ ihat_out,
                                              float* __restrict__ scal) {
  __shared__ __align__(16) u16 As[128 * LDA];
  __shared__ __align__(16) u16 Bs0[64 * LDA];
  __shared__ float rbuf[4];
  int col0 = blockIdx.x * 64, row0 = blockIdx.y * 128;
  f32x4 acc[2][4];
#pragma unroll
  for (int mi = 0; mi < 2; ++mi)
#pragma unroll
    for (int ni = 0; ni < 4; ++ni) acc[mi][ni] = (f32x4){0.f, 0.f, 0.f, 0.f};
  mfma_gemm<DREC, false>(r1_bf, Wr2, nullptr, row0, col0, acc, acc, As, Bs0, Bs0);
  EPILOGUE_IDX();
  float lsum = 0.f;
#pragma unroll
  for (int mi = 0; mi < 2; ++mi)
#pragma unroll
    for (int ni = 0; ni < 4; ++ni)
#pragma unroll
      for (int r = 0; r < 4; ++r) {
        int m = row0 + w * 32 + mi * 16 + fq * 4 + r;
        int n = col0 + ni * 16 + frow;
        float ih = 1.f / (1.f + expf(-acc[mi][ni][r]));
        ihat_out[(size_t)m * DIN + n] = ih;
        float d = I_t[(size_t)m * DIN + n] - ih;
        lsum += d * d;
      }
  float s = block_sum256(lsum, rbuf);
  if (tid == 0) atomicAdd(scal + 0, s * (1.f / ((float)BB * DIN)));
}

// ---------------------------------------------------------------------------
extern "C" void kernel_launch(void* const* d_in, const int* in_sizes, int n_in,
                              void* d_out, int out_size, void* d_ws,
                              size_t ws_size, hipStream_t stream) {
  const float* I_t       = (const float*)d_in[0];
  const float* h_m_1     = (const float*)d_in[1];
  const float* z_m_1     = (const float*)d_in[2];
  const float* theta_m_1 = (const float*)d_in[3];
  const float* eps_z     = (const float*)d_in[4];
  const float* eps_zhat  = (const float*)d_in[5];
  const float* W_post_mu = (const float*)d_in[6];
  const float* W_post_lv = (const float*)d_in[7];
  const float* W_z2h     = (const float*)d_in[8];
  const float* W_h2h     = (const float*)d_in[9];
  const float* W_prior_mu= (const float*)d_in[10];
  const float* W_prior_lv= (const float*)d_in[11];
  const float* W_i2t     = (const float*)d_in[12];
  const float* W_vip2t   = (const float*)d_in[13];
  const float* W_t2z     = (const float*)d_in[14];
  const float* W_rec1    = (const float*)d_in[15];
  const float* W_rec2    = (const float*)d_in[16];

  float* out = (float*)d_out;
  float* ihat = out + OFF_IHAT;
  float* zout = out + OFF_Z;
  float* hout = out + OFF_H;
  float* zhat = out + OFF_ZHAT;
  float* scal = out + OFF_SCAL;

  u16* ws_u = (u16*)d_ws;
  u16* I_bf = (u16*)ihat;              // scratch inside d_out, dead-last
  u16* h_bf = ws_u + WS_HBF;
  u16* zm1_bf = ws_u + WS_ZM1BF;
  u16* sigma_bf = zm1_bf;              // alias: zm1 dead after k_h
  u16* r1_bf = zm1_bf;                 // alias: sigma dead after k_theta
  u16* z_bf = h_bf;                    // alias: h_bf dead after k_prior
  float* theta_ws = (float*)((char*)d_ws + WS_THETA_BYTES);

  hipMemsetAsync(scal, 0, 3 * sizeof(float), stream);

  k_cvt<<<2048, 256, 0, stream>>>(I_t, h_m_1, z_m_1, W_post_mu, W_post_lv,
                                  W_z2h, W_h2h, W_prior_mu, W_prior_lv, W_i2t,
                                  W_vip2t, W_rec1, W_rec2, I_bf,
                                  ws_u + WS_HBF);

  dim3 g256(DZ / 64, BB / 128);    // 4 x 64
  dim3 g1024(DIN / 64, BB / 128);  // 16 x 64

  k_h<<<g256, 256, 0, stream>>>(zm1_bf, h_bf, ws_u + W_Z2H, ws_u + W_H2H, hout);
  k_prior<<<g256, 256, 0, stream>>>(h_bf, ws_u + W_PRM, ws_u + W_PRL, eps_zhat,
                                    zhat, sigma_bf);
  k_theta<<<BB / 64, 256, 0, stream>>>(I_bf, ws_u + W_I2T, sigma_bf,
                                       ws_u + W_VIP, theta_m_1, theta_ws);
  k_post<<<g256, 256, 0, stream>>>(I_bf, ws_u + W_PM, ws_u + W_PL, eps_z,
                                   theta_ws, W_t2z, zhat, zout, z_bf, scal);
  k_rec1<<<g256, 256, 0, stream>>>(z_bf, ws_u + W_R1, r1_bf);
  k_rec2<<<g1024, 256, 0, stream>>>(r1_bf, ws_u + W_R2, I_t, ihat, scal);
}